// Round 13
// baseline (997.971 us; speedup 1.0000x reference)
//
#include <hip/hip_runtime.h>

// Fused CircularBoundaryBlock:
//   out = relu(LN(x + W2 @ relu(W1 @ [roll(x,1), x, roll(x,-1)] + b1) + b2))
// B=4, N=65536, H=128, fp32 I/O, bf16 MFMA internally.
//
// v14 = v13 (wave-independent, zero steady-loop barriers) with the repack
// FIXED. v13's bug: __shfl returns the SOURCE lane's evaluation of the
// value expression; the cb-offset selector used the destination's g>>1,
// which the source lane cannot know (dests g=0 and g=2 share one source).
// Correct 2-round permutation schedule (16 shuffles/chunk, lane-verified):
//   Round A: dest g <- lane lA = l + 16*(2*(g&1) + (g>>1));
//            source sends pb[2ks2 + (g_src&1)][w]; slots j2 = 2*(g>>1)+w.
//   Round B: dest g <- lane lB = l + 16*(2*(g&1) + 1 - (g>>1));
//            source sends pb[2ks2 + 1-(g_src&1)][w]; slots j2 = 2*(1-(g>>1))+w.
// All pb/t.u indices compile-time static (rule #20) via ternary selects.
//
// Structure (v13): each wave owns 16 complete rows; W1/W2 fragment-ordered
// in LDS (130 KB) shared by 16 waves (1024-thr block, 1 block/CU, 16
// independent waves, no barriers in the loop); GEMM1 A-frags straight from
// global (rolls hit L2); LN wave-local (2 shfl_xor); fp32 residual from L2.

typedef __bf16 bf16x8 __attribute__((ext_vector_type(8)));
typedef float  f32x4  __attribute__((ext_vector_type(4)));

#define H      128
#define NB     65536
#define BLK    1024          // 16 waves
#define GRID   256           // 1 block/CU
#define RPW    64            // rows per wave: 4096 waves * 64 = 262144
#define CHUNK  16            // rows per wave-chunk (one MFMA row-tile)

union U8 { bf16x8 v; unsigned u[4]; };

static __device__ __forceinline__ unsigned pkbf(float a, float b) {
    union { __bf16 h; unsigned short u; } ua, ub;
    ua.h = (__bf16)a; ub.h = (__bf16)b;
    return ((unsigned)ub.u << 16) | (unsigned)ua.u;   // low = a, high = b
}

__global__ __launch_bounds__(BLK, 1)
void cbb_kernel(const float* __restrict__ x, const float* __restrict__ W1,
                const float* __restrict__ b1, const float* __restrict__ W2,
                const float* __restrict__ b2, const float* __restrict__ gamma,
                const float* __restrict__ beta, float* __restrict__ out) {
    // W1 frags 96 KB + W2 frags 32 KB + params 2 KB = ~130 KB
    __shared__ __align__(16) __bf16 w1s[12 * 8 * 512];
    __shared__ __align__(16) __bf16 w2s[4 * 8 * 512];
    __shared__ __align__(16) float s_b1[128], s_b2[128], s_gamma[128], s_beta[128];

    const int tid  = threadIdx.x;
    const int wid  = tid >> 6;        // 0..15
    const int lane = tid & 63;
    const int l    = lane & 15;       // row-within-chunk index
    const int g    = lane >> 4;       // quad

    if (tid < 128) {
        s_b1[tid] = b1[tid];       s_b2[tid]   = b2[tid];
        s_gamma[tid] = gamma[tid]; s_beta[tid] = beta[tid];
    }

    // ---- fill weight fragments (once; the ONLY barrier in the kernel) ----
    // frag (ks,cb): elem (le,j) = W[(ks*32 + (le>>4)*8 + j)*H + cb*16 + (le&15)]
    for (int idx = tid; idx < 65536; idx += BLK) {
        const int fid = idx >> 9;          // fragment id 0..127
        const int e   = idx & 511;
        const int le  = e >> 3, j = e & 7;
        const int lel = le & 15, leg = le >> 4;
        if (fid < 96) {
            const int ks = fid >> 3, cb = fid & 7;
            w1s[idx] = (__bf16)W1[(ks * 32 + leg * 8 + j) * H + cb * 16 + lel];
        } else {
            const int f2 = fid - 96;
            const int ks = f2 >> 3, cb = f2 & 7;
            w2s[f2 * 512 + e] = (__bf16)W2[(ks * 32 + leg * 8 + j) * H + cb * 16 + lel];
        }
    }
    __syncthreads();

    const __bf16* w1l = w1s + lane * 8;
    const __bf16* w2l = w2s + lane * 8;

    // repack shuffle sources (2-round permutation; see header)
    const int lA = l + 16 * (2 * (g & 1) + (g >> 1));
    const int lB = l + 16 * (2 * (g & 1) + 1 - (g >> 1));
    const bool odd = (g & 1) != 0;     // source-side cb selector
    const bool hi  = (g >> 1) != 0;    // destination-side slot selector

    const int wave_id = blockIdx.x * 16 + wid;   // 0..4095
    const int r0base  = wave_id * RPW;

    for (int c = 0; c < RPW / CHUNK; ++c) {
        const int r0 = r0base + c * CHUNK;       // 16-aligned; never straddles a batch
        const int bb = r0 >> 16;
        const int n0 = r0 & (NB - 1);
        const size_t rowbase = (size_t)bb * NB;

        // ---- GEMM1 (swapped): acc[cb][i] = h[row n0+l][col cb*16+g*4+i] ----
        // A-frag(ks): lane (l,g) = cat[row l][k = ks*32+g*8 .. +7], loaded
        // straight from global: row (n0+l+(ks>>2)-1) wrapped, col (ks&3)*32+g*8.
        f32x4 acc[8];
#pragma unroll
        for (int cb = 0; cb < 8; ++cb) acc[cb] = (f32x4){0.f, 0.f, 0.f, 0.f};

        float4 la, lb;
        {
            const int row = (n0 + l - 1) & (NB - 1);
            const float* p = x + (rowbase + row) * H + g * 8;
            la = *(const float4*)p; lb = *(const float4*)(p + 4);
        }
#pragma unroll
        for (int ks = 0; ks < 12; ++ks) {
            float4 na = la, nb2 = lb;
            if (ks < 11) {                        // 1-deep manual pipeline
                const int ks1 = ks + 1;
                const int row = (n0 + l + (ks1 >> 2) - 1) & (NB - 1);
                const float* p = x + (rowbase + row) * H + (ks1 & 3) * 32 + g * 8;
                na = *(const float4*)p; nb2 = *(const float4*)(p + 4);
            }
            bf16x8 af;
            af[0] = (__bf16)la.x; af[1] = (__bf16)la.y;
            af[2] = (__bf16)la.z; af[3] = (__bf16)la.w;
            af[4] = (__bf16)lb.x; af[5] = (__bf16)lb.y;
            af[6] = (__bf16)lb.z; af[7] = (__bf16)lb.w;
#pragma unroll
            for (int cb = 0; cb < 8; ++cb) {
                const bf16x8 wf = *(const bf16x8*)(w1l + (ks * 8 + cb) * 512);
                acc[cb] = __builtin_amdgcn_mfma_f32_16x16x32_bf16(wf, af, acc[cb], 0, 0, 0);
            }
            la = na; lb = nb2;
        }

        // ---- relu + bias, pack to bf16 pairs: pb[cb][w] = (h[..2w],h[..2w+1]) ----
        unsigned pb[8][2];
#pragma unroll
        for (int cb = 0; cb < 8; ++cb) {
            const f32x4 bq = *(const f32x4*)(s_b1 + cb * 16 + g * 4);
            const float v0 = fmaxf(acc[cb][0] + bq[0], 0.f);
            const float v1 = fmaxf(acc[cb][1] + bq[1], 0.f);
            const float v2 = fmaxf(acc[cb][2] + bq[2], 0.f);
            const float v3 = fmaxf(acc[cb][3] + bq[3], 0.f);
            pb[cb][0] = pkbf(v0, v1);
            pb[cb][1] = pkbf(v2, v3);
        }

        // ---- repack C-layout -> GEMM2 A-frags (fixed 2-round schedule) ----
        // pa[ks2] word j2 = h[row l][c = ks2*32 + g*8 + 2*j2, c+1].
        // Holder of h[cb*16+q*4+i] = lane (l,q), word pb[cb][i>>1].
        bf16x8 pa[4];
#pragma unroll
        for (int ks2 = 0; ks2 < 4; ++ks2) {
            // source-side values (each lane evaluates with ITS OWN g)
            const unsigned sA0 = odd ? pb[2 * ks2 + 1][0] : pb[2 * ks2][0];
            const unsigned sA1 = odd ? pb[2 * ks2 + 1][1] : pb[2 * ks2][1];
            const unsigned sB0 = odd ? pb[2 * ks2][0]     : pb[2 * ks2 + 1][0];
            const unsigned sB1 = odd ? pb[2 * ks2][1]     : pb[2 * ks2 + 1][1];
            const unsigned a0 = (unsigned)__shfl((int)sA0, lA);
            const unsigned a1 = (unsigned)__shfl((int)sA1, lA);
            const unsigned b0 = (unsigned)__shfl((int)sB0, lB);
            const unsigned b1 = (unsigned)__shfl((int)sB1, lB);
            U8 t;
            t.u[0] = hi ? b0 : a0;   // slot j2=0
            t.u[1] = hi ? b1 : a1;   // slot j2=1
            t.u[2] = hi ? a0 : b0;   // slot j2=2
            t.u[3] = hi ? a1 : b1;   // slot j2=3
            pa[ks2] = t.v;
        }

        // ---- GEMM2 (swapped): acc2[cb][i] = delta[row n0+l][col cb*16+g*4+i] ----
        f32x4 acc2[8];
#pragma unroll
        for (int cb = 0; cb < 8; ++cb) acc2[cb] = (f32x4){0.f, 0.f, 0.f, 0.f};
#pragma unroll
        for (int ks2 = 0; ks2 < 4; ++ks2) {
#pragma unroll
            for (int cb = 0; cb < 8; ++cb) {
                const bf16x8 wf = *(const bf16x8*)(w2l + (ks2 * 8 + cb) * 512);
                acc2[cb] = __builtin_amdgcn_mfma_f32_16x16x32_bf16(wf, pa[ks2], acc2[cb], 0, 0, 0);
            }
        }

        // ---- residual (fp32 x from L2) + LN partials, all in-wave ----
        const float* xr = x + (rowbase + n0 + l) * H;
        float s = 0.f, qq = 0.f;
#pragma unroll
        for (int cb = 0; cb < 8; ++cb) {
            const f32x4 xv = *(const f32x4*)(xr + cb * 16 + g * 4);
            const f32x4 bq = *(const f32x4*)(s_b2 + cb * 16 + g * 4);
#pragma unroll
            for (int i = 0; i < 4; ++i) {
                acc2[cb][i] += bq[i] + xv[i];
                s  += acc2[cb][i];
                qq += acc2[cb][i] * acc2[cb][i];
            }
        }
        s  += __shfl_xor(s, 16);  s  += __shfl_xor(s, 32);
        qq += __shfl_xor(qq, 16); qq += __shfl_xor(qq, 32);
        const float mu = s * (1.f / 128.f);
        const float var = qq * (1.f / 128.f) - mu * mu;
        const float rv = rsqrtf(var + 1e-5f);

        // ---- normalize + relu, store direct ----
        float* op = out + (rowbase + n0 + l) * H;
#pragma unroll
        for (int cb = 0; cb < 8; ++cb) {
            const f32x4 gm = *(const f32x4*)(s_gamma + cb * 16 + g * 4);
            const f32x4 bt = *(const f32x4*)(s_beta + cb * 16 + g * 4);
            f32x4 o;
#pragma unroll
            for (int i = 0; i < 4; ++i)
                o[i] = fmaxf((acc2[cb][i] - mu) * rv * gm[i] + bt[i], 0.f);
            *(f32x4*)(op + cb * 16 + g * 4) = o;
        }
    }
}

extern "C" void kernel_launch(void* const* d_in, const int* in_sizes, int n_in,
                              void* d_out, int out_size, void* d_ws, size_t ws_size,
                              hipStream_t stream) {
    const float* x     = (const float*)d_in[0];
    const float* W1    = (const float*)d_in[1];
    const float* b1    = (const float*)d_in[2];
    const float* W2    = (const float*)d_in[3];
    const float* b2    = (const float*)d_in[4];
    const float* gamma = (const float*)d_in[5];
    const float* beta  = (const float*)d_in[6];
    float* out = (float*)d_out;

    // 256 blocks x 1024 threads = 1 block/CU, 16 independent waves/CU
    cbb_kernel<<<GRID, BLK, 0, stream>>>(x, W1, b1, W2, b2, gamma, beta, out);
}

// Round 14
// 422.763 us; speedup vs baseline: 2.3606x; 2.3606x over previous
//
#include <hip/hip_runtime.h>

// Fused CircularBoundaryBlock:
//   out = relu(LN(x + W2 @ relu(W1 @ [roll(x,1), x, roll(x,-1)] + b1) + b2))
// B=4, N=65536, H=128, fp32 I/O, bf16 MFMA internally.
//
// v15 = v8 (best, 98us/dispatch) MINUS the x-staging phase.
//   v14 proved (correctness-passed) that GEMM1 A-frags can load directly
//   from global: cat[row][k] = x[row-1+(k>>7)][k&127], and x (134 MB) is
//   L3-resident so the 3x roll re-reads are cache-served. Cutting xs removes
//   per iteration: the stage phase (17 ds_writes + converts + prefetch
//   VALU), barrier B2 (3 -> 2 barriers/iter), the 36-reg xreg/xhalo
//   prefetch state, and the bf16 residual round-trip (residual now reads x
//   as fp32 -> MORE accurate). GEMM1's A-reads become 96 float4 global
//   loads issued inside the 96-MFMA loop, which hides their L2 latency;
//   2 independent blocks/CU cover the rest.
//   Register-band invariant (settled by v2/v4/v9/v10/v14): 8 waves/CU,
//   weights resident. LDS ~61 KB -> still 2 blocks/CU.
// Kept from v8: W1 frags in regs, W2 frags in LDS, swapped-operand MFMA,
// hs through LDS, LN-direct epilogue (ps2 partials, bpermute stats), direct
// f32x4 global store, biases/gamma/beta in tiny LDS, setprio, 256 thr,
// 512 blocks. Spill tripwire: symmetric FETCH+WRITE explosion -> revert v8.

typedef __bf16 bf16x8 __attribute__((ext_vector_type(8)));
typedef __bf16 bf16x4 __attribute__((ext_vector_type(4)));
typedef float  f32x4  __attribute__((ext_vector_type(4)));

#define H      128
#define NB     65536        // rows per batch
#define TILE   64
#define HSS    136          // h LDS stride (bf16 elems)
#define PSS    18           // ps2 stride (float2), 144 B: 16B-aligned rows
#define NTILES 4096         // 4 * 65536 / 64
#define GRID   512          // 2 blocks/CU * 256 CUs

__global__ __launch_bounds__(256, 2)
void cbb_kernel(const float* __restrict__ x, const float* __restrict__ W1,
                const float* __restrict__ b1, const float* __restrict__ W2,
                const float* __restrict__ b2, const float* __restrict__ gamma,
                const float* __restrict__ beta, float* __restrict__ out) {
    __shared__ __align__(16) __bf16 hs[64 * HSS];  // 17.4 KB
    __shared__ __align__(16) __bf16 w2s[16384];    // W2 frags, 32 KB
    __shared__ __align__(16) float2 ps2[64 * PSS]; // LN partials, 9.2 KB
    __shared__ __align__(16) float s_b1[128], s_b2[128], s_gamma[128], s_beta[128];

    const int tid  = threadIdx.x;
    const int wid  = tid >> 6;
    const int lane = tid & 63;
    const int l    = lane & 15;   // MFMA n index (tile row, after swap)
    const int g    = lane >> 4;   // MFMA quad
    const int col0 = wid * 32;

    if (tid < 128) {
        s_b1[tid] = b1[tid];   s_b2[tid]   = b2[tid];
        s_gamma[tid] = gamma[tid]; s_beta[tid] = beta[tid];
    }

    // ---- W1 B-fragments persistent in registers (this wave's 32-col slice) ----
    bf16x8 w1f[12][2];
#pragma unroll
    for (int ks = 0; ks < 12; ++ks) {
#pragma unroll
        for (int ct = 0; ct < 2; ++ct) {
            const int cc = col0 + ct * 16 + l;
            bf16x8 f;
#pragma unroll
            for (int j = 0; j < 8; ++j)
                f[j] = (__bf16)W1[(ks * 32 + g * 8 + j) * H + cc];
            w1f[ks][ct] = f;
        }
    }

    // ---- W2 B-fragments -> LDS, fragment-ordered (once per block) ----
    for (int idx = tid; idx < 16384; idx += 256) {
        const int j  = idx & 7;
        const int ln = (idx >> 3) & 63;
        const int ct = (idx >> 9) & 1;
        const int ks = (idx >> 10) & 3;
        const int w  = idx >> 12;
        const int row = ks * 32 + (ln >> 4) * 8 + j;
        const int col = w * 32 + ct * 16 + (ln & 15);
        w2s[idx] = (__bf16)W2[row * H + col];
    }
    const __bf16* w2w = w2s + wid * 4096;
    __syncthreads();   // weights staged (once)

    for (int t = blockIdx.x; t < NTILES; t += GRID) {
        const int b  = t >> 10;
        const int n0 = (t & 1023) << 6;
        const size_t rowbase = (size_t)b * NB;

        // ---- GEMM1 (swapped, A-frags direct from global/L2/L3) ----
        // acc[rt][ct] = h[hcol quad][tilerow]; cat k-index: row offset k>>7,
        // col k&127. For lane (l,g), ks: row = n0+rt*16+l+(ks>>2)-1 (wrap),
        // cols (ks&3)*32 + g*8 .. +7 (fp32 -> bf16 convert in-reg).
        f32x4 acc[4][2];
#pragma unroll
        for (int rt = 0; rt < 4; ++rt)
#pragma unroll
            for (int ct = 0; ct < 2; ++ct)
                acc[rt][ct] = (f32x4){0.f, 0.f, 0.f, 0.f};

        __builtin_amdgcn_s_setprio(1);
#pragma unroll
        for (int ks = 0; ks < 12; ++ks) {
            const int kc = (ks & 3) * 32 + g * 8;
            const int dr = (ks >> 2) - 1;
#pragma unroll
            for (int rt = 0; rt < 4; ++rt) {
                const int row = (n0 + rt * 16 + l + dr + NB) & (NB - 1);
                const float* p = x + (rowbase + row) * H + kc;
                const float4 fa = *(const float4*)p;
                const float4 fb = *(const float4*)(p + 4);
                bf16x8 a;
                a[0] = (__bf16)fa.x; a[1] = (__bf16)fa.y;
                a[2] = (__bf16)fa.z; a[3] = (__bf16)fa.w;
                a[4] = (__bf16)fb.x; a[5] = (__bf16)fb.y;
                a[6] = (__bf16)fb.z; a[7] = (__bf16)fb.w;
                acc[rt][0] = __builtin_amdgcn_mfma_f32_16x16x32_bf16(w1f[ks][0], a, acc[rt][0], 0, 0, 0);
                acc[rt][1] = __builtin_amdgcn_mfma_f32_16x16x32_bf16(w1f[ks][1], a, acc[rt][1], 0, 0, 0);
            }
        }
        __builtin_amdgcn_s_setprio(0);

        // relu + bias -> hs: lane holds cols col0+ct*16+g*4..+3 of row rt*16+l
        {
            const f32x4 b1q0 = *(const f32x4*)(s_b1 + col0 + g * 4);
            const f32x4 b1q1 = *(const f32x4*)(s_b1 + col0 + 16 + g * 4);
#pragma unroll
            for (int rt = 0; rt < 4; ++rt) {
                bf16x4 h0, h1;
#pragma unroll
                for (int i = 0; i < 4; ++i) {
                    h0[i] = (__bf16)fmaxf(acc[rt][0][i] + b1q0[i], 0.f);
                    h1[i] = (__bf16)fmaxf(acc[rt][1][i] + b1q1[i], 0.f);
                }
                *(bf16x4*)(hs + (rt * 16 + l) * HSS + col0 + g * 4)      = h0;
                *(bf16x4*)(hs + (rt * 16 + l) * HSS + col0 + 16 + g * 4) = h1;
            }
        }
        __syncthreads();  // B3: hs tile visible

        // ---- GEMM2 (swapped): delta[outcol quad][tilerow] ----
        f32x4 acc2[4][2];
#pragma unroll
        for (int rt = 0; rt < 4; ++rt)
#pragma unroll
            for (int ct = 0; ct < 2; ++ct)
                acc2[rt][ct] = (f32x4){0.f, 0.f, 0.f, 0.f};

        __builtin_amdgcn_s_setprio(1);
#pragma unroll
        for (int ks = 0; ks < 4; ++ks) {
            const bf16x8 wf0 = *(const bf16x8*)(w2w + ks * 1024 + lane * 8);
            const bf16x8 wf1 = *(const bf16x8*)(w2w + ks * 1024 + 512 + lane * 8);
#pragma unroll
            for (int rt = 0; rt < 4; ++rt) {
                const bf16x8 a = *(const bf16x8*)(hs + (rt * 16 + l) * HSS + ks * 32 + g * 8);
                acc2[rt][0] = __builtin_amdgcn_mfma_f32_16x16x32_bf16(wf0, a, acc2[rt][0], 0, 0, 0);
                acc2[rt][1] = __builtin_amdgcn_mfma_f32_16x16x32_bf16(wf1, a, acc2[rt][1], 0, 0, 0);
            }
        }
        __builtin_amdgcn_s_setprio(0);

        // ---- residual: v = x + delta + b2 (x fp32 direct from L2/L3) ----
        {
            const f32x4 b2q0 = *(const f32x4*)(s_b2 + col0 + g * 4);
            const f32x4 b2q1 = *(const f32x4*)(s_b2 + col0 + 16 + g * 4);
#pragma unroll
            for (int rt = 0; rt < 4; ++rt) {
                const float* xr = x + (rowbase + n0 + rt * 16 + l) * H + col0;
                const f32x4 xv0 = *(const f32x4*)(xr + g * 4);
                const f32x4 xv1 = *(const f32x4*)(xr + 16 + g * 4);
#pragma unroll
                for (int i = 0; i < 4; ++i) {
                    acc2[rt][0][i] += b2q0[i] + xv0[i];
                    acc2[rt][1][i] += b2q1[i] + xv1[i];
                }
            }
        }

        // ---- LN partials: per-lane (s, sum v^2) over its 8 cols, per rt ----
#pragma unroll
        for (int rt = 0; rt < 4; ++rt) {
            float s = 0.f, qq = 0.f;
#pragma unroll
            for (int ct = 0; ct < 2; ++ct)
#pragma unroll
                for (int i = 0; i < 4; ++i) {
                    const float v = acc2[rt][ct][i];
                    s += v; qq += v * v;
                }
            ps2[(rt * 16 + l) * PSS + wid * 4 + g] = make_float2(s, qq);
        }
        __syncthreads();  // B4: partials visible; frees hs for next iter

        // ---- row stats for assigned row (= lane), chunked reads ----
        float mu, rv;
        {
            const f32x4* pp = (const f32x4*)(ps2 + lane * PSS);  // 144B rows
            float S = 0.f, Q = 0.f;
#pragma unroll
            for (int j = 0; j < 4; ++j) {
                const f32x4 e0 = pp[2 * j];
                const f32x4 e1 = pp[2 * j + 1];
                S += (e0[0] + e0[2]) + (e1[0] + e1[2]);
                Q += (e0[1] + e0[3]) + (e1[1] + e1[3]);
            }
            mu = S * (1.f / 128.f);
            const float var = Q * (1.f / 128.f) - mu * mu;
            rv = rsqrtf(var + 1e-5f);
        }

        // ---- normalize + relu in-reg, store f32x4 direct to global ----
        {
            const f32x4 gm0 = *(const f32x4*)(s_gamma + col0 + g * 4);
            const f32x4 gm1 = *(const f32x4*)(s_gamma + col0 + 16 + g * 4);
            const f32x4 bt0 = *(const f32x4*)(s_beta + col0 + g * 4);
            const f32x4 bt1 = *(const f32x4*)(s_beta + col0 + 16 + g * 4);
#pragma unroll
            for (int rt = 0; rt < 4; ++rt) {
                const float mur = __shfl(mu, (lane & 15) + rt * 16);
                const float rvr = __shfl(rv, (lane & 15) + rt * 16);
                float* op = out + (rowbase + n0 + rt * 16 + l) * H + col0;
                f32x4 o0, o1;
#pragma unroll
                for (int i = 0; i < 4; ++i) {
                    o0[i] = fmaxf((acc2[rt][0][i] - mur) * rvr * gm0[i] + bt0[i], 0.f);
                    o1[i] = fmaxf((acc2[rt][1][i] - mur) * rvr * gm1[i] + bt1[i], 0.f);
                }
                *(f32x4*)(op + g * 4)      = o0;
                *(f32x4*)(op + 16 + g * 4) = o1;
            }
        }
    }
}

extern "C" void kernel_launch(void* const* d_in, const int* in_sizes, int n_in,
                              void* d_out, int out_size, void* d_ws, size_t ws_size,
                              hipStream_t stream) {
    const float* x     = (const float*)d_in[0];
    const float* W1    = (const float*)d_in[1];
    const float* b1    = (const float*)d_in[2];
    const float* W2    = (const float*)d_in[3];
    const float* b2    = (const float*)d_in[4];
    const float* gamma = (const float*)d_in[5];
    const float* beta  = (const float*)d_in[6];
    float* out = (float*)d_out;

    // 512 blocks = 2 resident blocks/CU * 256 CUs; grid-stride over 4096 tiles
    cbb_kernel<<<GRID, 256, 0, stream>>>(x, W1, b1, W2, b2, gamma, beta, out);
}

// Round 15
// 259.781 us; speedup vs baseline: 3.8416x; 1.6274x over previous
//
#include <hip/hip_runtime.h>

// Fused CircularBoundaryBlock:
//   out = relu(LN(x + W2 @ relu(W1 @ [roll(x,1), x, roll(x,-1)] + b1) + b2))
// B=4, N=65536, H=128, fp32 I/O, bf16 MFMA internally.
//
// v16 = v8 restored (best measured: 98us/dispatch, 260.6us bench).
// Session evidence (15 rounds): the op's live set (~120 regs) + resident
// weights pin execution in the 129-256-reg band -> 8 waves/CU (5 escape
// attempts spilled: v2/v4/v9/v10/v14). LDS staging of x is load-bearing
// (v15: direct global A-frags exposed L2 latency, -170%). Barrier-drain
// semantics (v12), LN software-pipelining (v11), and weight streaming
// (v2/v10) all measured neutral-or-worse. v8's structure is the measured
// optimum: 64-row tiles, 4 waves column-split, W1 frags in regs (AGPR),
// W2 frags in LDS, swapped-operand MFMA (lane-contiguous epilogues),
// T14 async stage split + halo prefetch, LN-direct epilogue (no vs
// buffer, ps2 partials + bpermute stats), direct f32x4 global stores,
// 3 barriers/iter, biases/gamma/beta in tiny LDS, setprio around MFMA.
// 256 thr, 512 blocks, 2 blocks/CU.

typedef __bf16 bf16x8 __attribute__((ext_vector_type(8)));
typedef __bf16 bf16x4 __attribute__((ext_vector_type(4)));
typedef float  f32x4  __attribute__((ext_vector_type(4)));

#define H      128
#define NB     65536        // rows per batch
#define TILE   64
#define XS     136          // x LDS stride (bf16 elems)
#define HSS    136          // h LDS stride (bf16 elems)
#define PSS    18           // ps2 stride (float2), 144 B: 16B-aligned rows
#define NTILES 4096         // 4 * 65536 / 64
#define GRID   512          // 2 blocks/CU * 256 CUs

__global__ __launch_bounds__(256, 2)
void cbb_kernel(const float* __restrict__ x, const float* __restrict__ W1,
                const float* __restrict__ b1, const float* __restrict__ W2,
                const float* __restrict__ b2, const float* __restrict__ gamma,
                const float* __restrict__ beta, float* __restrict__ out) {
    // xs (66*136 bf16) + hs (64*136 bf16) = 35360 B (no vs buffer)
    __shared__ __align__(16) char raw[(66 * XS + 64 * HSS) * 2];
    __bf16* xs = (__bf16*)raw;
    __bf16* hs = xs + 66 * XS;
    __shared__ __align__(16) __bf16 w2s[16384];    // W2 frags, 32 KB, persistent
    __shared__ __align__(16) float2 ps2[64 * PSS]; // LN partials, 9216 B
    __shared__ __align__(16) float s_b1[128], s_b2[128], s_gamma[128], s_beta[128];

    const int tid  = threadIdx.x;
    const int wid  = tid >> 6;
    const int lane = tid & 63;
    const int l    = lane & 15;   // MFMA n index (tile row, after swap)
    const int g    = lane >> 4;   // MFMA quad
    const int col0 = wid * 32;

    if (tid < 128) {
        s_b1[tid] = b1[tid];   s_b2[tid]   = b2[tid];
        s_gamma[tid] = gamma[tid]; s_beta[tid] = beta[tid];
    }

    // ---- W1 B-fragments persistent in registers (this wave's 32-col slice) ----
    bf16x8 w1f[12][2];
#pragma unroll
    for (int ks = 0; ks < 12; ++ks) {
#pragma unroll
        for (int ct = 0; ct < 2; ++ct) {
            const int cc = col0 + ct * 16 + l;
            bf16x8 f;
#pragma unroll
            for (int j = 0; j < 8; ++j)
                f[j] = (__bf16)W1[(ks * 32 + g * 8 + j) * H + cc];
            w1f[ks][ct] = f;
        }
    }

    // ---- W2 B-fragments -> LDS, fragment-ordered (once per block) ----
    // layout: w2s[w*4096 + ks*1024 + ct*512 + lane*8 + j]
    for (int idx = tid; idx < 16384; idx += 256) {
        const int j  = idx & 7;
        const int ln = (idx >> 3) & 63;
        const int ct = (idx >> 9) & 1;
        const int ks = (idx >> 10) & 3;
        const int w  = idx >> 12;
        const int row = ks * 32 + (ln >> 4) * 8 + j;
        const int col = w * 32 + ct * 16 + (ln & 15);
        w2s[idx] = (__bf16)W2[row * H + col];
    }
    const __bf16* w2w = w2s + wid * 4096;

    // ---- T14 prefetch: full 66-row halo tile (8 float4 + tid<64 halo) ----
    float4 xreg[8];
    float4 xhalo;
    {
        const int t  = blockIdx.x;
        const int b  = t >> 10;
        const int n0 = (t & 1023) << 6;
        const size_t rowbase = (size_t)b * NB;
#pragma unroll
        for (int s = 0; s < 8; ++s) {
            const int q = tid + s * 256;            // q < 2048 -> rows 0..63
            const int r = q >> 5, c = q & 31;
            const int grow = (n0 - 1 + r + NB) & (NB - 1);
            xreg[s] = *(const float4*)(x + ((rowbase + grow) * H + c * 4));
        }
        if (tid < 64) {                              // rows 64,65
            const int q = 2048 + tid;
            const int r = q >> 5, c = q & 31;
            const int grow = (n0 - 1 + r + NB) & (NB - 1);
            xhalo = *(const float4*)(x + ((rowbase + grow) * H + c * 4));
        }
    }

    for (int t = blockIdx.x; t < NTILES; t += GRID) {
        const int b  = t >> 10;
        const int n0 = (t & 1023) << 6;
        const size_t rowbase = (size_t)b * NB;

        // no loop-top barrier: prev-iter xs/hs readers are ordered by B4(ps2);
        // post-B4 work touches only ps2 + global.

        // ---- stage: consume prefetched regs -> xs (bf16) ----
#pragma unroll
        for (int s = 0; s < 8; ++s) {
            const int q = tid + s * 256;
            const int r = q >> 5, c = q & 31;
            bf16x4 v4;
            v4[0] = (__bf16)xreg[s].x; v4[1] = (__bf16)xreg[s].y;
            v4[2] = (__bf16)xreg[s].z; v4[3] = (__bf16)xreg[s].w;
            *(bf16x4*)(xs + r * XS + c * 4) = v4;
        }
        if (tid < 64) {
            const int q = 2048 + tid;
            const int r = q >> 5, c = q & 31;
            bf16x4 v4;
            v4[0] = (__bf16)xhalo.x; v4[1] = (__bf16)xhalo.y;
            v4[2] = (__bf16)xhalo.z; v4[3] = (__bf16)xhalo.w;
            *(bf16x4*)(xs + r * XS + c * 4) = v4;
        }
        __syncthreads();  // B2: xs tile visible

        // ---- issue next tile's loads; they fly under GEMM1/GEMM2/LN ----
        if (t + GRID < NTILES) {
            const int tn  = t + GRID;
            const int bn  = tn >> 10;
            const int n0n = (tn & 1023) << 6;
            const size_t rbn = (size_t)bn * NB;
#pragma unroll
            for (int s = 0; s < 8; ++s) {
                const int q = tid + s * 256;
                const int r = q >> 5, c = q & 31;
                const int grow = (n0n - 1 + r + NB) & (NB - 1);
                xreg[s] = *(const float4*)(x + ((rbn + grow) * H + c * 4));
            }
            if (tid < 64) {
                const int q = 2048 + tid;
                const int r = q >> 5, c = q & 31;
                const int grow = (n0n - 1 + r + NB) & (NB - 1);
                xhalo = *(const float4*)(x + ((rbn + grow) * H + c * 4));
            }
        }

        // ---- GEMM1 (swapped): acc[rt][ct] = D[hcol quad][tilerow] ----
        f32x4 acc[4][2];
#pragma unroll
        for (int rt = 0; rt < 4; ++rt)
#pragma unroll
            for (int ct = 0; ct < 2; ++ct)
                acc[rt][ct] = (f32x4){0.f, 0.f, 0.f, 0.f};

        __builtin_amdgcn_s_setprio(1);
#pragma unroll
        for (int ks = 0; ks < 12; ++ks) {
            const int k  = ks * 32 + g * 8;          // k in [0,384)
            const int ro = k >> 7, kc = k & 127;
#pragma unroll
            for (int rt = 0; rt < 4; ++rt) {
                const bf16x8 a = *(const bf16x8*)(xs + (rt * 16 + l + ro) * XS + kc);
                acc[rt][0] = __builtin_amdgcn_mfma_f32_16x16x32_bf16(w1f[ks][0], a, acc[rt][0], 0, 0, 0);
                acc[rt][1] = __builtin_amdgcn_mfma_f32_16x16x32_bf16(w1f[ks][1], a, acc[rt][1], 0, 0, 0);
            }
        }
        __builtin_amdgcn_s_setprio(0);

        // relu + bias -> hs: lane holds cols col0+ct*16+g*4..+3 of row rt*16+l
        {
            const f32x4 b1q0 = *(const f32x4*)(s_b1 + col0 + g * 4);
            const f32x4 b1q1 = *(const f32x4*)(s_b1 + col0 + 16 + g * 4);
#pragma unroll
            for (int rt = 0; rt < 4; ++rt) {
                bf16x4 h0, h1;
#pragma unroll
                for (int i = 0; i < 4; ++i) {
                    h0[i] = (__bf16)fmaxf(acc[rt][0][i] + b1q0[i], 0.f);
                    h1[i] = (__bf16)fmaxf(acc[rt][1][i] + b1q1[i], 0.f);
                }
                *(bf16x4*)(hs + (rt * 16 + l) * HSS + col0 + g * 4)      = h0;
                *(bf16x4*)(hs + (rt * 16 + l) * HSS + col0 + 16 + g * 4) = h1;
            }
        }
        __syncthreads();  // B3: hs tile visible

        // ---- GEMM2 (swapped): delta[outcol quad][tilerow] ----
        f32x4 acc2[4][2];
#pragma unroll
        for (int rt = 0; rt < 4; ++rt)
#pragma unroll
            for (int ct = 0; ct < 2; ++ct)
                acc2[rt][ct] = (f32x4){0.f, 0.f, 0.f, 0.f};

        __builtin_amdgcn_s_setprio(1);
#pragma unroll
        for (int ks = 0; ks < 4; ++ks) {
            const bf16x8 wf0 = *(const bf16x8*)(w2w + ks * 1024 + lane * 8);
            const bf16x8 wf1 = *(const bf16x8*)(w2w + ks * 1024 + 512 + lane * 8);
#pragma unroll
            for (int rt = 0; rt < 4; ++rt) {
                const bf16x8 a = *(const bf16x8*)(hs + (rt * 16 + l) * HSS + ks * 32 + g * 8);
                acc2[rt][0] = __builtin_amdgcn_mfma_f32_16x16x32_bf16(wf0, a, acc2[rt][0], 0, 0, 0);
                acc2[rt][1] = __builtin_amdgcn_mfma_f32_16x16x32_bf16(wf1, a, acc2[rt][1], 0, 0, 0);
            }
        }
        __builtin_amdgcn_s_setprio(0);

        // ---- residual: v = x + delta + b2 (vectorized b64 x re-read) ----
        {
            const f32x4 b2q0 = *(const f32x4*)(s_b2 + col0 + g * 4);
            const f32x4 b2q1 = *(const f32x4*)(s_b2 + col0 + 16 + g * 4);
#pragma unroll
            for (int rt = 0; rt < 4; ++rt) {
                const bf16x4 xv0 = *(const bf16x4*)(xs + (rt * 16 + l + 1) * XS + col0 + g * 4);
                const bf16x4 xv1 = *(const bf16x4*)(xs + (rt * 16 + l + 1) * XS + col0 + 16 + g * 4);
#pragma unroll
                for (int i = 0; i < 4; ++i) {
                    acc2[rt][0][i] += b2q0[i] + (float)xv0[i];
                    acc2[rt][1][i] += b2q1[i] + (float)xv1[i];
                }
            }
        }

        // ---- LN partials: per-lane (s, sum v^2) over its 8 cols, per rt ----
#pragma unroll
        for (int rt = 0; rt < 4; ++rt) {
            float s = 0.f, qq = 0.f;
#pragma unroll
            for (int ct = 0; ct < 2; ++ct)
#pragma unroll
                for (int i = 0; i < 4; ++i) {
                    const float v = acc2[rt][ct][i];
                    s += v; qq += v * v;
                }
            ps2[(rt * 16 + l) * PSS + wid * 4 + g] = make_float2(s, qq);
        }
        __syncthreads();  // B4: partials visible; also frees xs/hs for next iter

        // ---- row stats for assigned row (= lane), chunked reads ----
        float mu, rv;
        {
            const f32x4* pp = (const f32x4*)(ps2 + lane * PSS);  // 144B rows
            float S = 0.f, Q = 0.f;
#pragma unroll
            for (int j = 0; j < 4; ++j) {
                const f32x4 e0 = pp[2 * j];
                const f32x4 e1 = pp[2 * j + 1];
                S += (e0[0] + e0[2]) + (e1[0] + e1[2]);
                Q += (e0[1] + e0[3]) + (e1[1] + e1[3]);
            }
            mu = S * (1.f / 128.f);
            const float var = Q * (1.f / 128.f) - mu * mu;
            rv = rsqrtf(var + 1e-5f);
        }

        // ---- normalize + relu in-reg, store f32x4 direct to global ----
        {
            const f32x4 gm0 = *(const f32x4*)(s_gamma + col0 + g * 4);
            const f32x4 gm1 = *(const f32x4*)(s_gamma + col0 + 16 + g * 4);
            const f32x4 bt0 = *(const f32x4*)(s_beta + col0 + g * 4);
            const f32x4 bt1 = *(const f32x4*)(s_beta + col0 + 16 + g * 4);
#pragma unroll
            for (int rt = 0; rt < 4; ++rt) {
                const float mur = __shfl(mu, (lane & 15) + rt * 16);
                const float rvr = __shfl(rv, (lane & 15) + rt * 16);
                float* op = out + (rowbase + n0 + rt * 16 + l) * H + col0;
                f32x4 o0, o1;
#pragma unroll
                for (int i = 0; i < 4; ++i) {
                    o0[i] = fmaxf((acc2[rt][0][i] - mur) * rvr * gm0[i] + bt0[i], 0.f);
                    o1[i] = fmaxf((acc2[rt][1][i] - mur) * rvr * gm1[i] + bt1[i], 0.f);
                }
                *(f32x4*)(op + g * 4)      = o0;
                *(f32x4*)(op + 16 + g * 4) = o1;
            }
        }
    }
}

extern "C" void kernel_launch(void* const* d_in, const int* in_sizes, int n_in,
                              void* d_out, int out_size, void* d_ws, size_t ws_size,
                              hipStream_t stream) {
    const float* x     = (const float*)d_in[0];
    const float* W1    = (const float*)d_in[1];
    const float* b1    = (const float*)d_in[2];
    const float* W2    = (const float*)d_in[3];
    const float* b2    = (const float*)d_in[4];
    const float* gamma = (const float*)d_in[5];
    const float* beta  = (const float*)d_in[6];
    float* out = (float*)d_out;

    // 512 blocks = 2 resident blocks/CU * 256 CUs; grid-stride over 4096 tiles
    cbb_kernel<<<GRID, 256, 0, stream>>>(x, W1, b1, W2, b2, gamma, beta, out);
}